// Round 6
// baseline (6013.042 us; speedup 1.0000x reference)
//
#include <hip/hip_runtime.h>
#include <hip/hip_bf16.h>

#define BB 256
#define NN 2048
#define NSTEPS 64
#define DT_C 0.1f
#define BN_T (BB * NN)

typedef __attribute__((ext_vector_type(8))) short short8;
typedef __attribute__((ext_vector_type(4))) float floatx4;

__device__ __forceinline__ floatx4 mfma_bf16(short8 a, short8 b, floatx4 c) {
  return __builtin_amdgcn_mfma_f32_16x16x32_bf16(a, b, c, 0, 0, 0);
}

__device__ __forceinline__ short bf16bits(float f) {
  __hip_bfloat16 h = __float2bfloat16(f);
  return *reinterpret_cast<short*>(&h);
}

// ---------------- fragment-major layouts (verified rounds 4-5) ----------------
// frag(rf=row>>4, kc=k>>5), frag idx = rf*64+kc, 512 bf16/frag (1KB contiguous);
// in-frag: lane = (row&15) | (((k>>3)&3)<<4), elem = k&7.

__global__ __launch_bounds__(256) void convert_kernel(
    const float* __restrict__ src, __hip_bfloat16* __restrict__ dst) {
  const int g = blockIdx.x * 256 + threadIdx.x;
  const int frag = g >> 6, l = g & 63;
  const int j = (frag >> 6) * 16 + (l & 15);
  const int k = (frag & 63) * 32 + (l >> 4) * 8;
  const float* s = src + (size_t)j * NN + k;
  short8 v;
#pragma unroll
  for (int e = 0; e < 8; ++e) v[e] = bf16bits(s[e]);
  *(short8*)((short*)dst + (size_t)g * 8) = v;
}

__global__ __launch_bounds__(256) void init_kernel(
    const float* __restrict__ x0,
    __hip_bfloat16* __restrict__ U, __hip_bfloat16* __restrict__ PSI) {
  const int i = blockIdx.x * 256 + threadIdx.x;
  const int b = i >> 11, j = i & (NN - 1);
  const float r = fmaxf(x0[i], 0.f);
  const int dl = (b & 15) | (((j >> 3) & 3) << 4);
  const size_t fo = ((size_t)((b >> 4) * 64 + (j >> 5))) * 512 + dl * 8 + (j & 7);
  U[fo] = __float2bfloat16(r * r);   // u0 = relu(x0)*relu(x0)  (phi==g at t=0)
  PSI[fo] = __float2bfloat16(r);
}

#define LOADST(S, kc) \
  S##a0 = *(const short8*)(aP0 + (size_t)(kc) * 512); \
  S##a1 = *(const short8*)(aP1 + (size_t)(kc) * 512); \
  S##b0 = *(const short8*)(bP0 + (size_t)(kc) * 512); \
  S##b1 = *(const short8*)(bP1 + (size_t)(kc) * 512);
#define DOMFMA(S) \
  acc00 = mfma_bf16(S##a0, S##b0, acc00); \
  acc01 = mfma_bf16(S##a0, S##b1, acc01); \
  acc10 = mfma_bf16(S##a1, S##b0, acc10); \
  acc11 = mfma_bf16(S##a1, S##b1, acc11);

// Persistent cooperative kernel: all 64 steps, grid barrier between steps.
// Block: 64 rows x 32 cols, BOTH GEMMs. 8 waves: wv = g*4 + rw*2 + h
//   g: 0=W-GEMM(A=U), 1=T-GEMM(A=PSI); rw: row-half; h: K-half.
__global__ __launch_bounds__(512) void fused_kernel(
    const __hip_bfloat16* __restrict__ Wf, const __hip_bfloat16* __restrict__ Tf,
    const float* __restrict__ Wb, const float* __restrict__ Tb,
    const float* __restrict__ wp2s, const float* __restrict__ ws2p,
    const float* __restrict__ fri, const float* __restrict__ x0,
    float* __restrict__ S, float* __restrict__ P,
    __hip_bfloat16* __restrict__ U0, __hip_bfloat16* __restrict__ U1,
    __hip_bfloat16* __restrict__ PS0, __hip_bfloat16* __restrict__ PS1,
    float* __restrict__ out, unsigned* __restrict__ bar) {
  __shared__ float eb[8][32][36];   // per-wave 32x32 f32 partials, padded

  const int tid = threadIdx.x;
  const int lane = tid & 63, wv = tid >> 6;
  const int lane15 = lane & 15, kq = lane >> 4;
  const int g = wv >> 2, rw = (wv >> 1) & 1, h = wv & 1;

  // XCD-aware bijective swizzle: XCD x owns col-tiles x*8..x*8+7.
  const int x = blockIdx.x & 7, ii = blockIdx.x >> 3;
  const int colt = x * 8 + (ii >> 2), rowt = ii & 3;
  const int b0 = rowt * 64, j0 = colt * 32;

  const int rf0 = rowt * 4 + rw * 2;
  const int cf0 = colt * 2;
  const int kcb = h * 32;

  // weight streams: step-invariant
  const short* Bf = (const short*)(g == 0 ? Wf : Tf);
  const short* bP0 = Bf + ((size_t)cf0 * 64 + kcb) * 512 + lane * 8;
  const short* bP1 = Bf + ((size_t)(cf0 + 1) * 64 + kcb) * 512 + lane * 8;
  const size_t aOff0 = ((size_t)rf0 * 64 + kcb) * 512 + lane * 8;
  const size_t aOff1 = ((size_t)(rf0 + 1) * 64 + kcb) * 512 + lane * 8;

  // epilogue constants: step-invariant
  const int c = tid & 31, r4 = tid >> 5;
  const int j = j0 + c;
  const float Wbj = Wb[j], Tbj = Tb[j], wpj = wp2s[j], wsj = ws2p[j];
  int idx4[4], fo4[4];
  float fr4[4];
#pragma unroll
  for (int i = 0; i < 4; ++i) {
    const int r = r4 * 4 + i;
    const int b = b0 + r;
    idx4[i] = b * NN + j;
    fr4[i] = fri[idx4[i]];
    const int dl = (b & 15) | (((j >> 3) & 3) << 4);
    fo4[i] = ((b >> 4) * 64 + (j >> 5)) * 512 + dl * 8 + (j & 7);
  }

  float* xs = out + BN_T;

  for (int t = 0; t < NSTEPS; ++t) {
    const __hip_bfloat16* Uprev  = (t & 1) ? U1 : U0;
    const __hip_bfloat16* PSprev = (t & 1) ? PS1 : PS0;
    __hip_bfloat16* Unew  = (t & 1) ? U0 : U1;
    __hip_bfloat16* PSnew = (t & 1) ? PS0 : PS1;
    const float* Xprev = (t == 0) ? x0 : (xs + (size_t)(t - 1) * BN_T);
    const float* Sprev = (t == 0) ? x0 : S;
    const float* Pprev = (t == 0) ? x0 : P;
    float* xsout = xs + (size_t)t * BN_T;

    const short* Af = (const short*)(g == 0 ? Uprev : PSprev);
    const short* aP0 = Af + aOff0;
    const short* aP1 = Af + aOff1;

    floatx4 acc00 = {0.f, 0.f, 0.f, 0.f}, acc01 = {0.f, 0.f, 0.f, 0.f};
    floatx4 acc10 = {0.f, 0.f, 0.f, 0.f}, acc11 = {0.f, 0.f, 0.f, 0.f};

    short8 Aa0, Aa1, Ab0, Ab1, Ba0, Ba1, Bb0, Bb1, Ca0, Ca1, Cb0, Cb1;
    LOADST(A, 0) LOADST(B, 1) LOADST(C, 2)
    for (int kc = 0; kc < 27; kc += 3) {
      DOMFMA(A) LOADST(A, kc + 3)
      DOMFMA(B) LOADST(B, kc + 4)
      DOMFMA(C) LOADST(C, kc + 5)
    }
    DOMFMA(A) LOADST(A, 30)
    DOMFMA(B) LOADST(B, 31)
    DOMFMA(C) DOMFMA(A) DOMFMA(B)

#pragma unroll
    for (int r = 0; r < 4; ++r) {
      eb[wv][kq * 4 + r][lane15] = acc00[r];
      eb[wv][kq * 4 + r][16 + lane15] = acc01[r];
      eb[wv][16 + kq * 4 + r][lane15] = acc10[r];
      eb[wv][16 + kq * 4 + r][16 + lane15] = acc11[r];
    }
    __syncthreads();

#pragma unroll
    for (int i = 0; i < 4; ++i) {
      const int r = r4 * 4 + i;
      const int rh = r >> 5, rl = r & 31;
      const float m1 = eb[rh * 2 + 0][rl][c] + eb[rh * 2 + 1][rl][c];
      const float m2 = eb[4 + rh * 2 + 0][rl][c] + eb[4 + rh * 2 + 1][rl][c];
      const int idx = idx4[i];
      const float xv = Xprev[idx], s = Sprev[idx], p = Pprev[idx];
      const float phi = fmaxf(xv, 0.f), gg = fmaxf(s, 0.f), psi = fmaxf(p, 0.f);
      const float xn = xv + DT_C * (-xv + m1 + Wbj) * fr4[i];
      const float sn = p + DT_C * (-s + wpj * psi + phi);   // base is p (as in source)
      const float pn = p + DT_C * (-p + m2 + Tbj + wsj * gg);
      S[idx] = sn;
      P[idx] = pn;
      xsout[idx] = xn;
      if (t == NSTEPS - 1) out[idx] = xn;
      Unew[fo4[i]] = __float2bfloat16(fmaxf(xn, 0.f) * fmaxf(sn, 0.f));
      PSnew[fo4[i]] = __float2bfloat16(fmaxf(pn, 0.f));
    }

    if (t < NSTEPS - 1) {
      // grid barrier with device-scope release/acquire (cross-XCD U/PS exchange)
      __builtin_amdgcn_fence(__ATOMIC_RELEASE, "agent");
      __syncthreads();
      if (tid == 0) {
        __hip_atomic_fetch_add(bar, 1u, __ATOMIC_RELAXED, __HIP_MEMORY_SCOPE_AGENT);
        const unsigned target = 256u * (unsigned)(t + 1);
        while (__hip_atomic_load(bar, __ATOMIC_RELAXED, __HIP_MEMORY_SCOPE_AGENT) < target)
          __builtin_amdgcn_s_sleep(2);
      }
      __syncthreads();
      __builtin_amdgcn_fence(__ATOMIC_ACQUIRE, "agent");
    }
  }
}

extern "C" void kernel_launch(void* const* d_in, const int* in_sizes, int n_in,
                              void* d_out, int out_size, void* d_ws, size_t ws_size,
                              hipStream_t stream) {
  const float* x0   = (const float*)d_in[0];
  const float* fri  = (const float*)d_in[1];
  const float* Ww   = (const float*)d_in[2];
  const float* Wb   = (const float*)d_in[3];
  const float* Tw   = (const float*)d_in[4];
  const float* Tb   = (const float*)d_in[5];
  const float* wp2s = (const float*)d_in[6];
  const float* ws2p = (const float*)d_in[7];
  float* out = (float*)d_out;

  const size_t BN = (size_t)BB * NN;
  const size_t NW = (size_t)NN * NN;
  unsigned* bar = (unsigned*)d_ws;                       // 256 B reserved
  float* S = (float*)((char*)d_ws + 256);
  float* P = S + BN;
  __hip_bfloat16* U0  = (__hip_bfloat16*)(P + BN);
  __hip_bfloat16* U1  = U0 + BN;
  __hip_bfloat16* PS0 = U1 + BN;
  __hip_bfloat16* PS1 = PS0 + BN;
  __hip_bfloat16* Wf  = PS1 + BN;
  __hip_bfloat16* Tf  = Wf + NW;

  hipMemsetAsync(bar, 0, 256, stream);
  convert_kernel<<<(int)(NW / 2048), 256, 0, stream>>>(Ww, Wf);
  convert_kernel<<<(int)(NW / 2048), 256, 0, stream>>>(Tw, Tf);
  init_kernel<<<(int)(BN / 256), 256, 0, stream>>>(x0, U0, PS0);

  void* kargs[] = {
    (void*)&Wf, (void*)&Tf, (void*)&Wb, (void*)&Tb, (void*)&wp2s, (void*)&ws2p,
    (void*)&fri, (void*)&x0, (void*)&S, (void*)&P,
    (void*)&U0, (void*)&U1, (void*)&PS0, (void*)&PS1, (void*)&out, (void*)&bar
  };
  hipLaunchCooperativeKernel((const void*)fused_kernel, dim3(256), dim3(512),
                             kargs, 0, stream);
}

// Round 7
// 989.521 us; speedup vs baseline: 6.0767x; 6.0767x over previous
//
#include <hip/hip_runtime.h>
#include <hip/hip_bf16.h>

#define BB 256
#define NN 2048
#define NSTEPS 64
#define DT_C 0.1f

typedef __attribute__((ext_vector_type(8))) short short8;
typedef __attribute__((ext_vector_type(4))) short short4_t;
typedef __attribute__((ext_vector_type(4))) float floatx4;
typedef __attribute__((ext_vector_type(4))) float f32x4;

__device__ __forceinline__ floatx4 mfma_bf16(short8 a, short8 b, floatx4 c) {
  return __builtin_amdgcn_mfma_f32_16x16x32_bf16(a, b, c, 0, 0, 0);
}

__device__ __forceinline__ short bf16bits(float f) {
  __hip_bfloat16 h = __float2bfloat16(f);
  return *reinterpret_cast<short*>(&h);
}

// ---------------- fragment-major layouts (verified rounds 4-5) ----------------
// frag(rf=row>>4, kc=k>>5), frag idx = rf*64+kc, 512 bf16/frag (1KB contiguous);
// in-frag: lane = (row&15) | (((k>>3)&3)<<4), elem = k&7.

__global__ __launch_bounds__(256) void convert_kernel(
    const float* __restrict__ src, __hip_bfloat16* __restrict__ dst) {
  const int g = blockIdx.x * 256 + threadIdx.x;
  const int frag = g >> 6, l = g & 63;
  const int j = (frag >> 6) * 16 + (l & 15);
  const int k = (frag & 63) * 32 + (l >> 4) * 8;
  const float* s = src + (size_t)j * NN + k;
  short8 v;
#pragma unroll
  for (int e = 0; e < 8; ++e) v[e] = bf16bits(s[e]);
  *(short8*)((short*)dst + (size_t)g * 8) = v;
}

__global__ __launch_bounds__(256) void init_kernel(
    const float* __restrict__ x0,
    __hip_bfloat16* __restrict__ U, __hip_bfloat16* __restrict__ PSI) {
  const int i = blockIdx.x * 256 + threadIdx.x;
  const int b = i >> 11, j = i & (NN - 1);
  const float r = fmaxf(x0[i], 0.f);
  const int dl = (b & 15) | (((j >> 3) & 3) << 4);
  const size_t fo = ((size_t)((b >> 4) * 64 + (j >> 5))) * 512 + dl * 8 + (j & 7);
  U[fo] = __float2bfloat16(r * r);   // u0 = relu(x0)*relu(x0)  (phi==g at t=0)
  PSI[fo] = __float2bfloat16(r);
}

#define LOADST(S, kc) \
  S##a0 = *(const short8*)(aP0 + (size_t)(kc) * 512); \
  S##a1 = *(const short8*)(aP1 + (size_t)(kc) * 512); \
  S##b0 = *(const short8*)(bP0 + (size_t)(kc) * 512); \
  S##b1 = *(const short8*)(bP1 + (size_t)(kc) * 512);
#define DOMFMA(S) \
  acc00 = mfma_bf16(S##a0, S##b0, acc00); \
  acc01 = mfma_bf16(S##a0, S##b1, acc01); \
  acc10 = mfma_bf16(S##a1, S##b0, acc10); \
  acc11 = mfma_bf16(S##a1, S##b1, acc11);

// Block: 64 rows x 32 cols, BOTH GEMMs. 8 waves: wv = g*4 + rw*2 + h
//   g: 0=W-GEMM(A=U), 1=T-GEMM(A=PSI); rw: row-half (32 rows); h: K-half (1024).
// All 8 waves' global streams are disjoint -> zero redundant VMEM traffic.
// Depth-6 pipeline (24 x 1KB loads in flight); epilogue inputs preloaded
// before the K-loop; epilogue fully vectorized (float4/short4).
__global__ __launch_bounds__(512, 2) void step_kernel(
    const __hip_bfloat16* __restrict__ Wf, const __hip_bfloat16* __restrict__ Tf,
    const float* __restrict__ Wb, const float* __restrict__ Tb,
    const float* __restrict__ wp2s, const float* __restrict__ ws2p,
    const float* __restrict__ fri,
    const float* __restrict__ Xprev, const float* __restrict__ Sprev,
    const float* __restrict__ Pprev,
    const __hip_bfloat16* __restrict__ Uprev, const __hip_bfloat16* __restrict__ PSprev,
    float* __restrict__ Snew, float* __restrict__ Pnew,
    __hip_bfloat16* __restrict__ Unew, __hip_bfloat16* __restrict__ PSnew,
    float* __restrict__ xsout, float* __restrict__ outFin, int last) {
  __shared__ float eb[8][32][36];   // per-wave 32x32 f32 partials, padded

  const int tid = threadIdx.x;
  const int lane = tid & 63, wv = tid >> 6;
  const int lane15 = lane & 15, kq = lane >> 4;
  const int g = wv >> 2, rw = (wv >> 1) & 1, h = wv & 1;

  // XCD-aware bijective swizzle: XCD x owns col-tiles x*8..x*8+7 (2MB weights in L2).
  const int x = blockIdx.x & 7, ii = blockIdx.x >> 3;
  const int colt = x * 8 + (ii >> 2), rowt = ii & 3;
  const int b0 = rowt * 64, j0 = colt * 32;

  // ---- epilogue preloads: issue BEFORE the GEMM so latency hides under it ----
  const int erow = tid >> 3;          // 0..63
  const int c4 = (tid & 7) << 2;      // 0,4,...,28
  const int ej = j0 + c4;
  const size_t eidx = (size_t)(b0 + erow) * NN + ej;
  const f32x4 Wb4 = *(const f32x4*)(Wb + ej);
  const f32x4 Tb4 = *(const f32x4*)(Tb + ej);
  const f32x4 wp4 = *(const f32x4*)(wp2s + ej);
  const f32x4 ws4 = *(const f32x4*)(ws2p + ej);
  const f32x4 fr4 = *(const f32x4*)(fri + eidx);
  const f32x4 xv4 = *(const f32x4*)(Xprev + eidx);
  const f32x4 sv4 = *(const f32x4*)(Sprev + eidx);
  const f32x4 pv4 = *(const f32x4*)(Pprev + eidx);

  // ---- GEMM streams (disjoint per wave) ----
  const short* Af = (const short*)(g == 0 ? Uprev : PSprev);
  const short* Bf = (const short*)(g == 0 ? Wf : Tf);
  const int rf0 = rowt * 4 + rw * 2;   // A row-frag base (rows rw*32..+31)
  const int cf0 = colt * 2;            // B col-frag base (cols j0..+31)
  const int kcb = h * 32;              // K-half base (frag-k units)

  const short* aP0 = Af + ((size_t)rf0 * 64 + kcb) * 512 + lane * 8;
  const short* aP1 = Af + ((size_t)(rf0 + 1) * 64 + kcb) * 512 + lane * 8;
  const short* bP0 = Bf + ((size_t)cf0 * 64 + kcb) * 512 + lane * 8;
  const short* bP1 = Bf + ((size_t)(cf0 + 1) * 64 + kcb) * 512 + lane * 8;

  floatx4 acc00 = {0.f, 0.f, 0.f, 0.f}, acc01 = {0.f, 0.f, 0.f, 0.f};
  floatx4 acc10 = {0.f, 0.f, 0.f, 0.f}, acc11 = {0.f, 0.f, 0.f, 0.f};

  short8 Aa0, Aa1, Ab0, Ab1, Ba0, Ba1, Bb0, Bb1, Ca0, Ca1, Cb0, Cb1;
  short8 Da0, Da1, Db0, Db1, Ea0, Ea1, Eb0, Eb1, Fa0, Fa1, Fb0, Fb1;
  LOADST(A, 0) LOADST(B, 1) LOADST(C, 2) LOADST(D, 3) LOADST(E, 4) LOADST(F, 5)
  for (int kc = 0; kc < 24; kc += 6) {   // compute 0..23, load 6..29
    DOMFMA(A) LOADST(A, kc + 6)
    DOMFMA(B) LOADST(B, kc + 7)
    DOMFMA(C) LOADST(C, kc + 8)
    DOMFMA(D) LOADST(D, kc + 9)
    DOMFMA(E) LOADST(E, kc + 10)
    DOMFMA(F) LOADST(F, kc + 11)
  }
  DOMFMA(A) LOADST(A, 30)
  DOMFMA(B) LOADST(B, 31)
  DOMFMA(C) DOMFMA(D) DOMFMA(E) DOMFMA(F)
  DOMFMA(A) DOMFMA(B)                    // 32 k-iters total, no OOB loads

  // publish partials: eb[wv][local row][local col]
#pragma unroll
  for (int r = 0; r < 4; ++r) {
    eb[wv][kq * 4 + r][lane15] = acc00[r];
    eb[wv][kq * 4 + r][16 + lane15] = acc01[r];
    eb[wv][16 + kq * 4 + r][lane15] = acc10[r];
    eb[wv][16 + kq * 4 + r][16 + lane15] = acc11[r];
  }
  __syncthreads();

  // ---- vector epilogue: thread owns (row erow, cols ej..ej+3) ----
  const int rl = erow & 31, rh = erow >> 5;
  f32x4 m1, m2;
  {
    const f32x4 p0 = *(const f32x4*)&eb[rh * 2 + 0][rl][c4];
    const f32x4 p1 = *(const f32x4*)&eb[rh * 2 + 1][rl][c4];
    const f32x4 q0 = *(const f32x4*)&eb[4 + rh * 2 + 0][rl][c4];
    const f32x4 q1 = *(const f32x4*)&eb[4 + rh * 2 + 1][rl][c4];
    m1 = p0 + p1;
    m2 = q0 + q1;
  }
  f32x4 xn4, sn4, pn4;
  short4_t u4, ps4;
#pragma unroll
  for (int e = 0; e < 4; ++e) {
    const float xv = xv4[e], s = sv4[e], p = pv4[e];
    const float phi = fmaxf(xv, 0.f), gg = fmaxf(s, 0.f), psi = fmaxf(p, 0.f);
    const float xn = xv + DT_C * (-xv + m1[e] + Wb4[e]) * fr4[e];
    const float sn = p + DT_C * (-s + wp4[e] * psi + phi);   // base is p (as in source)
    const float pn = p + DT_C * (-p + m2[e] + Tb4[e] + ws4[e] * gg);
    xn4[e] = xn; sn4[e] = sn; pn4[e] = pn;
    u4[e] = bf16bits(fmaxf(xn, 0.f) * fmaxf(sn, 0.f));
    ps4[e] = bf16bits(fmaxf(pn, 0.f));
  }
  *(f32x4*)(Snew + eidx) = sn4;
  *(f32x4*)(Pnew + eidx) = pn4;
  *(f32x4*)(xsout + eidx) = xn4;
  if (last) *(f32x4*)(outFin + eidx) = xn4;
  // next-step operands, fragment-major (4 consecutive elems share dl group)
  const int b = b0 + erow;
  const int dl = (b & 15) | (((ej >> 3) & 3) << 4);
  const int fob = ((b >> 4) * 64 + (ej >> 5)) * 512 + dl * 8 + (ej & 7);
  *(short4_t*)((short*)Unew + fob) = u4;
  *(short4_t*)((short*)PSnew + fob) = ps4;
}

extern "C" void kernel_launch(void* const* d_in, const int* in_sizes, int n_in,
                              void* d_out, int out_size, void* d_ws, size_t ws_size,
                              hipStream_t stream) {
  const float* x0   = (const float*)d_in[0];
  const float* fri  = (const float*)d_in[1];
  const float* Ww   = (const float*)d_in[2];
  const float* Wb   = (const float*)d_in[3];
  const float* Tw   = (const float*)d_in[4];
  const float* Tb   = (const float*)d_in[5];
  const float* wp2s = (const float*)d_in[6];
  const float* ws2p = (const float*)d_in[7];
  float* out = (float*)d_out;

  const size_t BN = (size_t)BB * NN;
  const size_t NW = (size_t)NN * NN;
  float* S = (float*)d_ws;
  float* P = S + BN;
  __hip_bfloat16* U0  = (__hip_bfloat16*)(P + BN);
  __hip_bfloat16* U1  = U0 + BN;
  __hip_bfloat16* PS0 = U1 + BN;
  __hip_bfloat16* PS1 = PS0 + BN;
  __hip_bfloat16* Wf  = PS1 + BN;
  __hip_bfloat16* Tf  = Wf + NW;

  convert_kernel<<<(int)(NW / 2048), 256, 0, stream>>>(Ww, Wf);
  convert_kernel<<<(int)(NW / 2048), 256, 0, stream>>>(Tw, Tf);
  init_kernel<<<(int)(BN / 256), 256, 0, stream>>>(x0, U0, PS0);

  float* xs = out + BN;  // xs[t] = out + BN + t*BN
  for (int t = 0; t < NSTEPS; ++t) {
    const float* Xprev = (t == 0) ? x0 : (xs + (size_t)(t - 1) * BN);
    const float* Sprev = (t == 0) ? x0 : S;
    const float* Pprev = (t == 0) ? x0 : P;
    const __hip_bfloat16* Uprev  = (t & 1) ? U1 : U0;
    const __hip_bfloat16* PSprev = (t & 1) ? PS1 : PS0;
    __hip_bfloat16* Unew  = (t & 1) ? U0 : U1;
    __hip_bfloat16* PSnew = (t & 1) ? PS0 : PS1;
    step_kernel<<<256, 512, 0, stream>>>(Wf, Tf, Wb, Tb, wp2s, ws2p, fri,
                                         Xprev, Sprev, Pprev, Uprev, PSprev,
                                         S, P, Unew, PSnew,
                                         xs + (size_t)t * BN, out,
                                         (t == NSTEPS - 1) ? 1 : 0);
  }
}